// Round 8
// baseline (80.426 us; speedup 1.0000x reference)
//
#include <hip/hip_runtime.h>

// Problem constants (from reference setup_inputs)
#define LATDIM 128     // d
#define ANUM   64      // anchor sets A
#define NNODES 10000   // N
#define PERIOD 625     // period of (64*i mod 10000); gcd(64,10000)=16
#define TN     32      // n per main block
#define PPB    8       // anchors per P-block
#define PBLK   (ANUM / PPB)   // 8 P-blocks
#define TBLK   157            // T2-blocks; block t owns s in {t, t+157k}, k<4
#define WP4    33      // W_s row stride in float4 units (132 floats)

// ---------------------------------------------------------------------------
// Verified algebra (r3/r4/r6/r7 passed, absmax 9.8e-4):
//   out[n,o] = sum_a dists[a,n]*Ps[a,o] + T2b[n%625,o]   (Ps = P/64)
//   Ps[a,o]  = (1/A)*sum_k E[anchor[a],k]*W[o,k]
//   T2b[s,o] = b[o] + (1/A)*sum_k S[s,k]*W[o,128+k], S[s,k]=sum_a E[(64s+a)%N,k]
//
// r7 (MEASURED -4.0us): T-phase window regrouping via 64*157==48 (mod 1e4):
// windows {t,t+157,t+314,t+471} live in one contiguous 208-row span.
// r8 delta: main a-loop loads dists as 4x float4 (uniform addr) instead of
// 16 scalar loads — issue-count cut ~35%; P pre-scaled by 1/64 at prep so
// the epilogue drops 16 muls. Everything else byte-identical to r7.
// r5 lesson kept: no cross-block flags, no p[64] VGPR arrays.
// ---------------------------------------------------------------------------

__global__ __launch_bounds__(256) void prep_kernel(
    const float* __restrict__ embeds,   // [N, d] fp32
    const float* __restrict__ W,        // [d, 2d] fp32 row-major
    const float* __restrict__ b,        // [d] fp32
    const int*   __restrict__ anchor,   // [A] int32
    float* __restrict__ P,              // [A, d]   (ws) — stores P/64
    float* __restrict__ T2b)            // [625, d] (ws)
{
    __shared__ float W_s[128 * 4 * WP4];    // 128 rows x 132 floats = 66 KB
    __shared__ float X_s[PPB * LATDIM];     // phase-2 inputs (4 KB)
    __shared__ float R_s[PPB * LATDIM];     // cross-half partials (4 KB)
    const int tid = threadIdx.x;            // 0..255
    const bool isP = (blockIdx.x < PBLK);
    const int off = isP ? 0 : LATDIM;       // which W half
    float4* W_s4 = (float4*)W_s;
    const float4* X_s4 = (const float4*)X_s;
    const int col = tid & 127;              // output channel / column
    const int h   = tid >> 7;               // half: 0 or 1

    // Stage W-half into LDS (coalesced float4; pad-33 rows: 0 conflicts
    // measured r4/r6/r7).
    #pragma unroll
    for (int it = 0; it < 16; ++it) {
        int f = it * 256 + tid;          // 0..4095
        int r = f >> 5, c4 = f & 31;
        W_s4[r * WP4 + c4] =
            *(const float4*)(W + r * (2 * LATDIM) + off + 4 * c4);
    }

    if (isP) {
        const int a0 = blockIdx.x * PPB;
        #pragma unroll
        for (int it = 0; it < 4; ++it) {
            int idx = it * 256 + tid;        // 0..1023
            int j = idx >> 7, c = idx & 127;
            X_s[j * LATDIM + c] = embeds[(size_t)anchor[a0 + j] * LATDIM + c];
        }
        __syncthreads();   // covers W_s too

        // Phase 2, split-k across halves.
        float acc[PPB] = {};
        #pragma unroll
        for (int k4 = 0; k4 < 16; ++k4) {
            int kk = h * 16 + k4;
            float4 w = W_s4[col * WP4 + kk];
            #pragma unroll
            for (int j = 0; j < PPB; ++j) {
                float4 e = X_s4[j * 32 + kk];   // broadcast
                acc[j] += e.x*w.x + e.y*w.y + e.z*w.z + e.w*w.w;
            }
        }
        if (h == 1) {
            #pragma unroll
            for (int j = 0; j < PPB; ++j) R_s[j * LATDIM + col] = acc[j];
        }
        __syncthreads();
        if (h == 0) {
            #pragma unroll
            for (int j = 0; j < PPB; ++j)
                P[(size_t)(a0 + j) * LATDIM + col] =
                    (acc[j] + R_s[j * LATDIM + col]) * (1.0f / ANUM);
        }
    } else {
        const int t = blockIdx.x - PBLK;     // 0..156
        const int rbase = 64 * t;            // span start (<= 9984)
        // Phase 1: one sweep over 208 contiguous rows; segment masks route
        // each row into the window(s) containing it. Half h takes r = h mod 2.
        float acc[4] = {};
        #define LDROW(r_) ({ int row_ = rbase + (r_);                        \
                             if (row_ >= NNODES) row_ -= NNODES;             \
                             embeds[(size_t)row_ * LATDIM + col]; })
        #pragma unroll
        for (int i = 0; i < 24; ++i) {                 // [0,48) -> w0
            acc[0] += LDROW(h + 2 * i);
        }
        #pragma unroll
        for (int i = 0; i < 8; ++i) {                  // [48,64) -> w0,w1
            float v = LDROW(48 + h + 2 * i); acc[0] += v; acc[1] += v;
        }
        #pragma unroll
        for (int i = 0; i < 16; ++i) {                 // [64,96) -> w1
            acc[1] += LDROW(64 + h + 2 * i);
        }
        #pragma unroll
        for (int i = 0; i < 8; ++i) {                  // [96,112) -> w1,w2
            float v = LDROW(96 + h + 2 * i); acc[1] += v; acc[2] += v;
        }
        #pragma unroll
        for (int i = 0; i < 16; ++i) {                 // [112,144) -> w2
            acc[2] += LDROW(112 + h + 2 * i);
        }
        #pragma unroll
        for (int i = 0; i < 8; ++i) {                  // [144,160) -> w2,w3
            float v = LDROW(144 + h + 2 * i); acc[2] += v; acc[3] += v;
        }
        #pragma unroll
        for (int i = 0; i < 24; ++i) {                 // [160,208) -> w3
            acc[3] += LDROW(160 + h + 2 * i);
        }
        #undef LDROW

        if (h == 1) {
            #pragma unroll
            for (int j = 0; j < 4; ++j) R_s[j * LATDIM + col] = acc[j];
        }
        __syncthreads();   // covers W_s too
        if (h == 0) {
            #pragma unroll
            for (int j = 0; j < 4; ++j)
                X_s[j * LATDIM + col] = acc[j] + R_s[j * LATDIM + col];
        }
        __syncthreads();

        // Phase 2, split-k across halves.
        float acc2[4] = {};
        #pragma unroll
        for (int k4 = 0; k4 < 16; ++k4) {
            int kk = h * 16 + k4;
            float4 w = W_s4[col * WP4 + kk];
            #pragma unroll
            for (int j = 0; j < 4; ++j) {
                float4 s = X_s4[j * 32 + kk];   // broadcast
                acc2[j] += s.x*w.x + s.y*w.y + s.z*w.z + s.w*w.w;
            }
        }
        if (h == 1) {
            #pragma unroll
            for (int j = 0; j < 4; ++j) R_s[j * LATDIM + col] = acc2[j];
        }
        __syncthreads();
        if (h == 0) {
            const float bias = b[col];
            #pragma unroll
            for (int j = 0; j < 4; ++j) {
                int s = t + 157 * j;            // unique s per (t,j)
                if (s < PERIOD)
                    T2b[(size_t)s * LATDIM + col] =
                        bias + (acc2[j] + R_s[j * LATDIM + col]) * (1.0f / ANUM);
            }
        }
    }
}

// out[n,o] = sum_a dists[a,n] * Ps[a,o] + T2b[n%625, o]   (Ps pre-scaled)
// r8: dists row segment read as 4x float4 (wave-uniform addresses).
__global__ __launch_bounds__(256) void main_kernel(
    const float* __restrict__ dists,    // [A, N] fp32
    const float* __restrict__ P,        // [A, d]  (pre-scaled by 1/64)
    const float* __restrict__ T2b,      // [625, d]
    float* __restrict__ out)            // [N, d] fp32
{
    __shared__ float P_s[ANUM * LATDIM];   // 32 KB
    const int tid = threadIdx.x;

    {   // stage P, coalesced float4
        float4* P_s4 = (float4*)P_s;
        const float4* Pg = (const float4*)P;
        #pragma unroll
        for (int it = 0; it < (ANUM * LATDIM / 4) / 256; ++it)
            P_s4[it * 256 + tid] = Pg[it * 256 + tid];
    }
    __syncthreads();

    const int lane = tid & 63;
    const int w    = __builtin_amdgcn_readfirstlane(tid >> 6);  // uniform 0..3
    const int o    = (w & 1) * 64 + lane;   // output channel
    const int nc   = w >> 1;                // n-chunk within block
    int nb = blockIdx.x * TN + nc * 16;     // uniform chunk base
    const bool live = (nb + 16) <= NNODES;  // chunks 16-aligned; N%16==0
    if (!live) nb = NNODES - 16;            // clamp loads; stores guarded

    float acc[16] = {};
    for (int a = 0; a < ANUM; ++a) {
        const float p = P_s[a * LATDIM + o];                 // per-lane LDS
        const float4* __restrict__ drow =
            (const float4*)(dists + (size_t)a * NNODES + nb); // nb % 4 == 0
        #pragma unroll
        for (int j4 = 0; j4 < 4; ++j4) {
            float4 d = drow[j4];                             // uniform ldx4
            acc[j4 * 4 + 0] += d.x * p;
            acc[j4 * 4 + 1] += d.y * p;
            acc[j4 * 4 + 2] += d.z * p;
            acc[j4 * 4 + 3] += d.w * p;
        }
    }

    if (live) {
        #pragma unroll
        for (int j = 0; j < 16; ++j) {
            const int n = nb + j;
            const int s = n % PERIOD;
            out[(size_t)n * LATDIM + o] =
                acc[j] + T2b[(size_t)s * LATDIM + o];
        }
    }
}

extern "C" void kernel_launch(void* const* d_in, const int* in_sizes, int n_in,
                              void* d_out, int out_size, void* d_ws, size_t ws_size,
                              hipStream_t stream) {
    const float* embeds = (const float*)d_in[0];   // [10000,128] fp32
    const float* dists  = (const float*)d_in[1];   // [64,10000]  fp32
    const float* W      = (const float*)d_in[2];   // [128,256]   fp32
    const float* b      = (const float*)d_in[3];   // [128]       fp32
    const int*   anchor = (const int*)d_in[4];     // [64]        int32
    float* out = (float*)d_out;                    // [10000,128] fp32

    float* P   = (float*)d_ws;            // 64*128 floats   = 32 KB (P/64)
    float* T2b = P + ANUM * LATDIM;       // 625*128 floats  = 320 KB

    prep_kernel<<<PBLK + TBLK, 256, 0, stream>>>(embeds, W, b, anchor, P, T2b);
    main_kernel<<<(NNODES + TN - 1) / TN, 256, 0, stream>>>(dists, P, T2b, out);
}